// Round 2
// baseline (139.170 us; speedup 1.0000x reference)
//
#include <hip/hip_runtime.h>
#include <stdint.h>

// LocallyConnected1d: out[b,c,o] = (1/8) * sum_{i<64,k<8} x[b,i,4o+k] * w[c,i,o,k]
// B=128, CIN=64, COUT=64, OUT_DIM=256, K=8, S=4, L=1028. fp32 in/out.
//
// R2 design (latency-bound fix): grid 1024 = 256 o × 4 batch-quarters,
// 4 blocks/CU. x staged to LDS once (one barrier total); w loaded direct
// global->reg in the K-loop (8 contiguous floats per lane per k-step),
// mfma_f32_16x16x32_bf16, each wave = 1 c-tile × 2 b-tiles.

#define B_    128
#define CIN_  64
#define COUT_ 64
#define OD_   256
#define K_    8
#define S_    4
#define L_    1028

#define MB    32             // batch rows per block
#define KDIM  512            // CIN * K
#define LDK   (KDIM + 8)     // +8 shorts pad -> 4-bank row shift, b128 reads optimal

typedef __attribute__((ext_vector_type(8))) short bf16x8;   // 8 bf16 (4 VGPRs)
typedef __attribute__((ext_vector_type(4))) float floatx4;  // MFMA accumulator

__device__ __forceinline__ unsigned short f32_to_bf16(float f) {
    union { float f; uint32_t u; } v; v.f = f;
    uint32_t u = v.u;
    u += 0x7FFFu + ((u >> 16) & 1u);   // round-to-nearest-even
    return (unsigned short)(u >> 16);
}

__global__ __launch_bounds__(256, 4)
void lc1d_r2_kernel(const float* __restrict__ x,
                    const float* __restrict__ w,
                    float* __restrict__ out) {
    // 32 * 520 * 2 = 33280 B -> 4 blocks/CU fit in 160 KiB LDS
    __shared__ __align__(16) unsigned short Ax[MB * LDK];

    const int tid = threadIdx.x;
    const int blk = blockIdx.x;
    // XCD swizzle: same-o blocks (4 bq) and 32 consecutive o's per XCD so
    // w lines (o-interleaved) and overlapping x windows share that XCD's L2.
    const int o  = ((blk & 7) << 5) | ((blk >> 3) & 31);
    const int bq = blk >> 8;            // 0..3
    const int b0 = bq * MB;

    const int wave = tid >> 6;
    const int lane = tid & 63;
    const int quad = lane >> 4;
    const int m16  = lane & 15;

    // ---- stage x once: MB rows x (64 i x 8 k) = 2048 runs of 8 floats; 8 runs/thread
    #pragma unroll
    for (int it = 0; it < 8; ++it) {
        const int run = it * 256 + tid;   // 0..2047
        const int i   = run & 63;
        const int b   = run >> 6;         // 0..31
        const float* src = x + ((size_t)(b0 + b) * CIN_ + i) * L_ + o * S_;
        const float4 v0 = *(const float4*)(src);
        const float4 v1 = *(const float4*)(src + 4);
        bf16x8 sv;
        sv[0] = (short)f32_to_bf16(v0.x); sv[1] = (short)f32_to_bf16(v0.y);
        sv[2] = (short)f32_to_bf16(v0.z); sv[3] = (short)f32_to_bf16(v0.w);
        sv[4] = (short)f32_to_bf16(v1.x); sv[5] = (short)f32_to_bf16(v1.y);
        sv[6] = (short)f32_to_bf16(v1.z); sv[7] = (short)f32_to_bf16(v1.w);
        *(bf16x8*)&Ax[b * LDK + i * 8] = sv;   // kk = i*8 + k, b128 write, conflict-free
    }

    floatx4 acc0 = (floatx4){0.f, 0.f, 0.f, 0.f};
    floatx4 acc1 = (floatx4){0.f, 0.f, 0.f, 0.f};

    __syncthreads();   // the only barrier in the kernel

    // this wave's output column c and its w base: w[c][i][o][k], 8 contiguous floats per (c,i)
    const int c = wave * 16 + m16;
    const float* wbase = w + (size_t)c * (CIN_ * OD_ * K_) + (size_t)o * K_;

    #pragma unroll
    for (int kt = 0; kt < 16; ++kt) {        // K = 512 = 16 steps of 32
        const int i = kt * 4 + quad;
        const float* wsrc = wbase + (size_t)i * (OD_ * K_);
        const float4 w0 = *(const float4*)(wsrc);
        const float4 w1 = *(const float4*)(wsrc + 4);
        bf16x8 bfrag;
        bfrag[0] = (short)f32_to_bf16(w0.x); bfrag[1] = (short)f32_to_bf16(w0.y);
        bfrag[2] = (short)f32_to_bf16(w0.z); bfrag[3] = (short)f32_to_bf16(w0.w);
        bfrag[4] = (short)f32_to_bf16(w1.x); bfrag[5] = (short)f32_to_bf16(w1.y);
        bfrag[6] = (short)f32_to_bf16(w1.z); bfrag[7] = (short)f32_to_bf16(w1.w);

        const bf16x8 a0 = *(const bf16x8*)&Ax[(m16)      * LDK + kt * 32 + quad * 8];
        const bf16x8 a1 = *(const bf16x8*)&Ax[(16 + m16) * LDK + kt * 32 + quad * 8];

        acc0 = __builtin_amdgcn_mfma_f32_16x16x32_bf16(a0, bfrag, acc0, 0, 0, 0);
        acc1 = __builtin_amdgcn_mfma_f32_16x16x32_bf16(a1, bfrag, acc1, 0, 0, 0);
    }

    // ---- epilogue: D layout col=lane&15 (n=c offset), row=quad*4+reg (b); scale 1/sqrt(64)
    #pragma unroll
    for (int r = 0; r < 4; ++r) {
        const int br = b0 + quad * 4 + r;
        out[((size_t)br        * COUT_ + c) * OD_ + o] = acc0[r] * 0.125f;
        out[((size_t)(br + 16) * COUT_ + c) * OD_ + o] = acc1[r] * 0.125f;
    }
}

extern "C" void kernel_launch(void* const* d_in, const int* in_sizes, int n_in,
                              void* d_out, int out_size, void* d_ws, size_t ws_size,
                              hipStream_t stream) {
    const float* x = (const float*)d_in[0];   // (128, 64, 1028)
    const float* w = (const float*)d_in[1];   // (1, 64, 64, 256, 8)
    float* out = (float*)d_out;               // (128, 64, 256)
    hipLaunchKernelGGL(lc1d_r2_kernel, dim3(1024), dim3(256), 0, stream, x, w, out);
}

// Round 3
// 126.686 us; speedup vs baseline: 1.0985x; 1.0985x over previous
//
#include <hip/hip_runtime.h>
#include <stdint.h>

// LocallyConnected1d: out[b,c,o] = (1/8) * sum_{i<64,k<8} x[b,i,4o+k] * w[c,i,o,k]
// B=128, CIN=64, COUT=64, OUT_DIM=256, K=8, S=4, L=1028. fp32 in/out.
//
// R3: o-quad tiling for coalescing. Block = (o-quad, 16 b, 32 c), grid 1024.
// w reads: 128B contiguous runs per (c,i). x reads: 80B runs per (b,i).
// K chunked by i (16/chunk), register-double-buffered staging, LDS holds
// bf16 tiles (x replicated per o-local so A-frags are one aligned b128).

#define B_    128
#define CIN_  64
#define COUT_ 64
#define OD_   256
#define K_    8
#define L_    1028

#define OT 4              // o per block (one per wave)
#define MB 16             // b per block
#define CT 32             // c per block
#define IC 16             // i per K-chunk
#define NCH (CIN_ / IC)   // 4 chunks

// LDS layouts (units: bf16 elements)
#define WI_STR  (CT * K_ + 8)          // 264: i-stride in w_lds (16B pad)
#define WLO_STR (IC * WI_STR + 8)      // 4232: o-local stride (bank skew)
#define XI_STR  (MB * K_ + 8)          // 136: i-stride in x_lds
#define XLO_STR (IC * XI_STR + 8)      // 2184: o-local stride

typedef __attribute__((ext_vector_type(8))) short bf16x8;   // 4 VGPRs
typedef __attribute__((ext_vector_type(4))) float floatx4;  // MFMA acc

__device__ __forceinline__ unsigned short f32_to_bf16(float f) {
    union { float f; uint32_t u; } v; v.f = f;
    uint32_t u = v.u;
    u += 0x7FFFu + ((u >> 16) & 1u);   // round-to-nearest-even
    return (unsigned short)(u >> 16);
}

__global__ __launch_bounds__(256, 3)
void lc1d_r3_kernel(const float* __restrict__ x,
                    const float* __restrict__ w,
                    float* __restrict__ out) {
    __shared__ __align__(16) unsigned short w_lds[OT * WLO_STR]; // 16928 el = 33856 B
    __shared__ __align__(16) unsigned short x_lds[OT * XLO_STR]; //  8736 el = 17472 B

    const int tid  = threadIdx.x;
    const int blk  = blockIdx.x;
    const int oq   = blk & 63;          // o-quad id; blk%8 == oq%8 -> same-oq blocks share XCD
    const int rest = blk >> 6;
    const int chc  = rest & 1;          // c half
    const int bq   = rest >> 1;         // 0..7
    const int b0   = bq * MB;
    const int c0   = chc * CT;

    const int wave = tid >> 6;          // o-local (0..3)
    const int lane = tid & 63;
    const int quad = lane >> 4;
    const int m16  = lane & 15;

    // staged-register buffers (held across compute for reg-level dbuf)
    float4 wreg[16];
    float4 xreg[5];

    // ---- staging helpers -------------------------------------------------
    auto load_chunk = [&](int ic) {
        const int i0 = ic * IC;
        #pragma unroll
        for (int it = 0; it < 16; ++it) {          // w: 32c x 16i x 8 f4-units
            const int u   = it * 256 + tid;
            const int t   = u & 7;                 // f4 within 128B run
            const int run = u >> 3;
            const int i   = run & 15;
            const int c   = run >> 4;              // 0..31
            wreg[it] = *(const float4*)(w +
                (((size_t)(c0 + c) * CIN_ + i0 + i) * OD_ + oq * OT) * K_ + t * 4);
        }
        #pragma unroll
        for (int it = 0; it < 5; ++it) {           // x: 16b x 16i rows x 5 f4
            const int u   = it * 256 + tid;
            const int t   = u % 5;                 // f4 within 80B row
            const int row = u / 5;
            const int i   = row & 15;
            const int b   = row >> 4;
            xreg[it] = *(const float4*)(x +
                ((size_t)(b0 + b) * CIN_ + i0 + i) * L_ + oq * 16 + t * 4);
        }
    };

    auto store_chunk = [&]() {
        #pragma unroll
        for (int it = 0; it < 16; ++it) {
            const int u   = it * 256 + tid;
            const int t   = u & 7;
            const int run = u >> 3;
            const int i   = run & 15;
            const int c   = run >> 4;
            const int lo  = t >> 1;                // o-local
            const int kh  = t & 1;                 // k half
            const float4 v = wreg[it];
            ushort4 sv = make_ushort4(f32_to_bf16(v.x), f32_to_bf16(v.y),
                                      f32_to_bf16(v.z), f32_to_bf16(v.w));
            *(ushort4*)&w_lds[lo * WLO_STR + i * WI_STR + c * K_ + kh * 4] = sv;
        }
        #pragma unroll
        for (int it = 0; it < 5; ++it) {
            const int u   = it * 256 + tid;
            const int t   = u % 5;                 // window floats l = t*4..t*4+3
            const int row = u / 5;
            const int i   = row & 15;
            const int b   = row >> 4;
            const float4 v = xreg[it];
            ushort4 sv = make_ushort4(f32_to_bf16(v.x), f32_to_bf16(v.y),
                                      f32_to_bf16(v.z), f32_to_bf16(v.w));
            // x replicated per o-local: l = t*4 lands at (lo, kh) with t = lo+kh
            if (t < 4)   // (lo=t,   k=0..3)
                *(ushort4*)&x_lds[t * XLO_STR + i * XI_STR + b * K_] = sv;
            if (t > 0)   // (lo=t-1, k=4..7)
                *(ushort4*)&x_lds[(t - 1) * XLO_STR + i * XI_STR + b * K_ + 4] = sv;
        }
    };

    // ---- main ------------------------------------------------------------
    floatx4 acc0 = (floatx4){0.f, 0.f, 0.f, 0.f};
    floatx4 acc1 = (floatx4){0.f, 0.f, 0.f, 0.f};

    load_chunk(0);
    store_chunk();
    __syncthreads();

    #pragma unroll
    for (int ch = 0; ch < NCH; ++ch) {
        if (ch + 1 < NCH) load_chunk(ch + 1);      // prefetch next chunk -> regs

        #pragma unroll
        for (int kt = 0; kt < 4; ++kt) {           // K-chunk 128 = 4 steps of 32
            const int i_l = kt * 4 + quad;         // kk = i_l*8 + j
            const bf16x8 af = *(const bf16x8*)
                &x_lds[wave * XLO_STR + i_l * XI_STR + m16 * K_];
            const bf16x8 bf0 = *(const bf16x8*)
                &w_lds[wave * WLO_STR + i_l * WI_STR + m16 * K_];
            const bf16x8 bf1 = *(const bf16x8*)
                &w_lds[wave * WLO_STR + i_l * WI_STR + (16 + m16) * K_];
            acc0 = __builtin_amdgcn_mfma_f32_16x16x32_bf16(af, bf0, acc0, 0, 0, 0);
            acc1 = __builtin_amdgcn_mfma_f32_16x16x32_bf16(af, bf1, acc1, 0, 0, 0);
        }
        __syncthreads();                           // all LDS reads done
        if (ch + 1 < NCH) { store_chunk(); __syncthreads(); }
    }

    // ---- epilogue: D col=lane&15 (c), row=quad*4+reg (b); scale 1/sqrt(64)
    const int o_g = oq * OT + wave;
    #pragma unroll
    for (int r = 0; r < 4; ++r) {
        const int b = b0 + quad * 4 + r;
        out[((size_t)b * COUT_ + c0 + m16)      * OD_ + o_g] = acc0[r] * 0.125f;
        out[((size_t)b * COUT_ + c0 + 16 + m16) * OD_ + o_g] = acc1[r] * 0.125f;
    }
}

extern "C" void kernel_launch(void* const* d_in, const int* in_sizes, int n_in,
                              void* d_out, int out_size, void* d_ws, size_t ws_size,
                              hipStream_t stream) {
    const float* x = (const float*)d_in[0];   // (128, 64, 1028)
    const float* w = (const float*)d_in[1];   // (1, 64, 64, 256, 8)
    float* out = (float*)d_out;               // (128, 64, 256)
    hipLaunchKernelGGL(lc1d_r3_kernel, dim3(1024), dim3(256), 0, stream, x, w, out);
}

// Round 4
// 115.748 us; speedup vs baseline: 1.2023x; 1.0945x over previous
//
#include <hip/hip_runtime.h>
#include <stdint.h>

// LocallyConnected1d: out[b,c,o] = (1/8) * sum_{i<64,k<8} x[b,i,4o+k] * w[c,i,o,k]
// B=128, CIN=64, COUT=64, OUT_DIM=256, K=8, S=4, L=1028. fp32 in/out.
//
// R4: two-phase. K1 transposes+converts w into bf16 workspace laid out EXACTLY
// as K2's LDS B-tile (bank-XOR baked in), so K2's w staging is a flat
// global_load_lds dwordx4 copy (zero VALU). K2: block = (o-pair q, b-quarter),
// grid 512 (2 blocks/CU), x read direct fp32 (windows shared by the o-pair),
// mfma_f32_16x16x32_bf16. XCD swizzle: q-ranges pinned per XCD so the 2.1 MB
// wb slab L2-caches and out-lines (16 consecutive o) merge in one L2.

#define B_    128
#define CIN_  64
#define COUT_ 64
#define OD_   256
#define K_    8
#define L_    1028

// wb layout: [q 128][ch 4][o_lo 2][c 64][gs 16][k 8] bf16, gs = i_loc ^ (c&7)
#define WB_PER_Q  65536
#define WB_PER_CH 16384

#define ASTR 20   // A_lds row stride in bf16 elems (40 B: non-pow2 -> <=2-way banks)

typedef __attribute__((ext_vector_type(8))) short bf16x8;
typedef __attribute__((ext_vector_type(4))) short short4v;
typedef __attribute__((ext_vector_type(4))) float floatx4;

__device__ __forceinline__ unsigned short f32_to_bf16(float f) {
    union { float f; uint32_t u; } v; v.f = f;
    uint32_t u = v.u;
    u += 0x7FFFu + ((u >> 16) & 1u);   // round-to-nearest-even
    return (unsigned short)(u >> 16);
}

// ---------------- K1: w fp32 -> wb bf16 (transpose + swizzle) ----------------
// grid 512 = 8 c-tiles(8) x 4 i-tiles(16) x 16 o-tiles(16). 256 threads.
__global__ __launch_bounds__(256, 2)
void lc1d_wprep(const float* __restrict__ w, unsigned short* __restrict__ wb) {
    __shared__ __align__(16) unsigned short tile[128 * 136];  // (c,i) rows x (16o x 8k), pad 8

    const int tid = threadIdx.x;
    const int bx  = blockIdx.x;
    const int c0  = (bx & 7) * 8;
    const int ch  = (bx >> 3) & 3;
    const int i0  = ch * 16;
    const int ot  = bx >> 5;           // 0..15
    const int o0  = ot * 16;
    const int q0  = ot * 8;

    // read: 128 rows (c,i) x 512 B contiguous (16 o x 8 k floats)
    #pragma unroll
    for (int it = 0; it < 16; ++it) {
        const int u   = it * 256 + tid;
        const int t   = u & 31;         // float4 within row
        const int row = u >> 5;         // cL*16 + iL
        const int iL  = row & 15;
        const int cL  = row >> 4;
        const float4 v = *(const float4*)(w +
            (size_t)((c0 + cL) * CIN_ + (i0 + iL)) * (OD_ * K_) + o0 * K_ + t * 4);
        ushort4 sv = make_ushort4(f32_to_bf16(v.x), f32_to_bf16(v.y),
                                  f32_to_bf16(v.z), f32_to_bf16(v.w));
        *(ushort4*)&tile[row * 136 + t * 4] = sv;
    }
    __syncthreads();

    // write: granule (qL, o_lo, cL, gs) -> contiguous 16 B stores in wb order
    #pragma unroll
    for (int it = 0; it < 8; ++it) {
        const int u    = it * 256 + tid;
        const int gs   = u & 15;
        const int cL   = (u >> 4) & 7;
        const int o_lo = (u >> 7) & 1;
        const int qL   = u >> 8;        // 0..7
        const int c    = c0 + cL;
        const int iL   = gs ^ (c & 7);  // bank-XOR baked into stored position
        const int row  = cL * 16 + iL;
        const int o_loc = qL * 2 + o_lo;
        const bf16x8 vv = *(const bf16x8*)&tile[row * 136 + o_loc * 8];
        const size_t dst = (size_t)(q0 + qL) * WB_PER_Q + (size_t)ch * WB_PER_CH
                         + ((size_t)((o_lo * 64 + c) * 16 + gs) << 3);
        *(bf16x8*)&wb[dst] = vv;
    }
}

// ---------------- K2: GEMM. block = (q, b-quarter), grid 512 ----------------
__global__ __launch_bounds__(256, 2)
void lc1d_gemm(const float* __restrict__ x,
               const unsigned short* __restrict__ wb,
               float* __restrict__ out) {
    __shared__ __align__(16) unsigned short Bl[16384];           // 32 KB, flat = wb chunk
    __shared__ __align__(16) unsigned short Al[16 * 32 * ASTR];  // 20 KB

    const int tid = threadIdx.x;
    const int blk = blockIdx.x;
    // XCD swizzle: XCD k hosts q in [16k,16k+16) for all b-quarters
    const int q   = (blk & 7) * 16 + ((blk >> 3) & 15);
    const int bq  = blk >> 7;           // 0..3
    const int b0  = bq * 32;

    const int wave = tid >> 6;
    const int lane = tid & 63;
    const int quad = lane >> 4;
    const int l16  = lane & 15;
    const int o_lo = wave & 1;          // which o of the pair
    const int ms   = wave >> 1;         // m-stripe (16 b rows)

    floatx4 acc[4];
    #pragma unroll
    for (int nt = 0; nt < 4; ++nt) acc[nt] = (floatx4){0.f, 0.f, 0.f, 0.f};

    for (int ch = 0; ch < 4; ++ch) {
        // ---- w staging: flat async copy wb[q][ch] -> Bl (32 KB), zero VALU ----
        const char* wsrc = (const char*)(wb + (size_t)q * WB_PER_Q + (size_t)ch * WB_PER_CH);
        #pragma unroll
        for (int j = 0; j < 8; ++j) {
            const int off = wave * 8192 + j * 1024;
            auto gp = (const __attribute__((address_space(1))) uint32_t*)(wsrc + off + lane * 16);
            auto lp = (__attribute__((address_space(3))) uint32_t*)((char*)&Bl[0] + off);
            __builtin_amdgcn_global_load_lds(gp, lp, 16, 0, 0);
        }

        // ---- x staging: rows (b,i) x 12 floats [8q, 8q+12) covering both o's ----
        #pragma unroll
        for (int it = 0; it < 8; ++it) {
            const int u   = it * 256 + tid;
            const int t   = u & 3;          // float4 within row; t==3 unused/masked
            const int row = u >> 2;         // 0..511
            const int iL  = row & 15;
            const int b   = row >> 4;       // 0..31
            if (t < 3) {
                const float4 v = *(const float4*)(x +
                    (size_t)((b0 + b) * CIN_ + ch * 16 + iL) * L_ + q * 8 + t * 4);
                ushort4 sv = make_ushort4(f32_to_bf16(v.x), f32_to_bf16(v.y),
                                          f32_to_bf16(v.z), f32_to_bf16(v.w));
                *(ushort4*)&Al[(iL * 32 + b) * ASTR + t * 4] = sv;
            }
        }
        __syncthreads();   // drains vmcnt (DMA) + lgkm (LDS stores)

        // ---- compute: 4 k-steps of 32 (i_loc = kt*4+quad, k=quad*8+j) ----
        #pragma unroll
        for (int kt = 0; kt < 4; ++kt) {
            const int i_l   = kt * 4 + quad;
            const int abase = (i_l * 32 + ms * 16 + l16) * ASTR + o_lo * 4;
            const short4v a_lo = *(const short4v*)&Al[abase];
            const short4v a_hi = *(const short4v*)&Al[abase + 4];
            bf16x8 af;
            af[0] = a_lo[0]; af[1] = a_lo[1]; af[2] = a_lo[2]; af[3] = a_lo[3];
            af[4] = a_hi[0]; af[5] = a_hi[1]; af[6] = a_hi[2]; af[7] = a_hi[3];
            #pragma unroll
            for (int nt = 0; nt < 4; ++nt) {
                const int c  = nt * 16 + l16;
                const int gs = i_l ^ (c & 7);
                const bf16x8 bf = *(const bf16x8*)&Bl[((o_lo * 64 + c) * 16 + gs) << 3];
                acc[nt] = __builtin_amdgcn_mfma_f32_16x16x32_bf16(af, bf, acc[nt], 0, 0, 0);
            }
        }
        __syncthreads();   // LDS reads done before next chunk overwrites
    }

    // ---- epilogue: D col=lane&15 (c), row=quad*4+reg (b); scale 1/sqrt(64) ----
    const int o_g = q * 2 + o_lo;
    #pragma unroll
    for (int nt = 0; nt < 4; ++nt) {
        const int c = nt * 16 + l16;
        #pragma unroll
        for (int r = 0; r < 4; ++r) {
            const int b = b0 + ms * 16 + quad * 4 + r;
            out[((size_t)b * COUT_ + c) * OD_ + o_g] = acc[nt][r] * 0.125f;
        }
    }
}

extern "C" void kernel_launch(void* const* d_in, const int* in_sizes, int n_in,
                              void* d_out, int out_size, void* d_ws, size_t ws_size,
                              hipStream_t stream) {
    const float* x = (const float*)d_in[0];   // (128, 64, 1028)
    const float* w = (const float*)d_in[1];   // (1, 64, 64, 256, 8)
    float* out = (float*)d_out;               // (128, 64, 256)
    unsigned short* wb = (unsigned short*)d_ws; // 16.8 MB bf16 workspace

    hipLaunchKernelGGL(lc1d_wprep, dim3(512), dim3(256), 0, stream, w, wb);
    hipLaunchKernelGGL(lc1d_gemm,  dim3(512), dim3(256), 0, stream, x, wb, out);
}